// Round 10
// baseline (3791.652 us; speedup 1.0000x reference)
//
#include <hip/hip_runtime.h>

// RoutingCapsules on MI355X (gfx950)
// x: [B=32, Nin=2048, Din=16] f32
// W: [1, Nin=2048, Nout=64, Dout=32, Din=16] f32
// out v: [B=32, Nout=64, Dout=32] f32
//
// 3 fused W-sweeps (u_hat recomputed, never materialized):
//   pass1: c uniform     -> s1 -> v1   (round-8 coalesced kernel, proven)
//   pass2: logits=u.v1   -> s2 -> v2   (wave-softmax kernel, two-sweep)
//   pass3: logits=u.(v1+v2)   -> v3 = out
//
// Round-10: round 9's lane=o mapping had the right softmax (in-wave, no
// barriers) but spilled by holding u[32]+acc[32]+temps live (865 MB scratch).
// Fix: never hold u -- sweep 1 computes the logit streaming W 16 regs at a
// time; after softmax, sweep 2 RE-READS the W row (L1/L2-hot) and accumulates
// c*u_d directly. asm memory-clobber between sweeps prevents the compiler
// from CSE-ing u across the softmax (which would re-create the spill).

#define B_   32
#define NIN  2048
#define DIN  16
#define NOUT 64
#define DOUT 32
#define BQ   8                          // batches per block
#define NCHB 16                         // n per block
#define CG   (NIN / NCHB)               // 128 chunk-groups
#define NBLK (CG * (B_ / BQ))           // 512 blocks
#define TPB  1024                       // pass1 / fallback kernel
#define TPB2 512                        // pass2/3 wave-softmax kernel
#define PART_PER_BLK (BQ * NOUT * DOUT / 2)   // 8192 float2 per block (64 KB)

// ---------------- round-8 kernel (pass1 + atomic fallback) ----------------
template<int PASS, bool ATOMIC>
__global__ __launch_bounds__(TPB)
void caps_pass(const float* __restrict__ W, const float* __restrict__ x,
               const float* __restrict__ v_in, float* __restrict__ s_out,
               float2* __restrict__ part)
{
    const int t    = threadIdx.x;
    const int o    = t >> 4;
    const int dg   = t & 15;
    const int d0   = dg << 1;
    const int lane = t & 63;
    const int wid  = t >> 6;

    const int bid  = blockIdx.x;
    const int xcd  = bid & 7;
    const int j    = bid >> 3;
    const int cg   = xcd * (CG / 8) + (j >> 2);
    const int quad = j & 3;
    const int nbase = cg * NCHB;
    const int bbase = quad * BQ;

    __shared__ float4 xs[BQ][NCHB * DIN / 4];

    if (t < BQ * NCHB * DIN / 4) {
        const int bb = t >> 6;
        const int k  = t & 63;
        xs[bb][k] = ((const float4*)x)[(size_t)(bbase + bb) * (NIN * DIN / 4)
                                       + (size_t)nbase * (DIN / 4) + k];
    }

    float acc0[BQ], acc1[BQ];
#pragma unroll
    for (int bb = 0; bb < BQ; ++bb) { acc0[bb] = 0.f; acc1[bb] = 0.f; }

    __syncthreads();

    if constexpr (PASS == 1) {
        for (int nn = 0; nn < NCHB; ++nn) {
            const float4* wp = (const float4*)(W +
                (((size_t)(nbase + nn) * NOUT + o) * DOUT + d0) * DIN);
            float4 w[8];
#pragma unroll
            for (int q = 0; q < 8; ++q) w[q] = wp[q];
#pragma unroll
            for (int bb = 0; bb < BQ; ++bb) {
                const float4* xr = &xs[bb][nn * 4];
                float u0 = 0.f, u1 = 0.f;
#pragma unroll
                for (int q = 0; q < 4; ++q) {
                    const float4 xv = xr[q];
                    u0 += w[q].x*xv.x + w[q].y*xv.y + w[q].z*xv.z + w[q].w*xv.w;
                    u1 += w[4+q].x*xv.x + w[4+q].y*xv.y + w[4+q].z*xv.z + w[4+q].w*xv.w;
                }
                acc0[bb] += u0;
                acc1[bb] += u1;
            }
        }
    } else {
        __shared__ float  lg[BQ * NOUT];
        __shared__ float  cs[BQ * NOUT];
        __shared__ float2 ustash[BQ][TPB];
        for (int nn = 0; nn < NCHB; ++nn) {
            const float4* wp = (const float4*)(W +
                (((size_t)(nbase + nn) * NOUT + o) * DOUT + d0) * DIN);
            float4 w[8];
#pragma unroll
            for (int q = 0; q < 8; ++q) w[q] = wp[q];
#pragma unroll
            for (int bb = 0; bb < BQ; ++bb) {
                const float4* xr = &xs[bb][nn * 4];
                float u0 = 0.f, u1 = 0.f;
#pragma unroll
                for (int q = 0; q < 4; ++q) {
                    const float4 xv = xr[q];
                    u0 += w[q].x*xv.x + w[q].y*xv.y + w[q].z*xv.z + w[q].w*xv.w;
                    u1 += w[4+q].x*xv.x + w[4+q].y*xv.y + w[4+q].z*xv.z + w[4+q].w*xv.w;
                }
                const float2 vv = ((const float2*)v_in)[
                    (size_t)(bbase + bb) * (NOUT * DOUT / 2) + o * (DOUT / 2) + dg];
                float p = u0 * vv.x + u1 * vv.y;
                p += __shfl_xor(p, 1);
                p += __shfl_xor(p, 2);
                p += __shfl_xor(p, 4);
                p += __shfl_xor(p, 8);
                if (dg == 0) lg[bb * NOUT + o] = p;
                ustash[bb][t] = make_float2(u0, u1);
            }
            __syncthreads();
            if (wid < BQ) {
                const float e = __expf(lg[wid * NOUT + lane]);
                float sm = e;
#pragma unroll
                for (int m = 1; m < 64; m <<= 1) sm += __shfl_xor(sm, m);
                cs[wid * NOUT + lane] = e / sm;
            }
            __syncthreads();
#pragma unroll
            for (int bb = 0; bb < BQ; ++bb) {
                const float c = cs[bb * NOUT + o];
                const float2 u = ustash[bb][t];
                acc0[bb] += c * u.x;
                acc1[bb] += c * u.y;
            }
        }
    }

    const float scale = (PASS == 1) ? (1.0f / 64.0f) : 1.0f;
    if constexpr (ATOMIC) {
#pragma unroll
        for (int bb = 0; bb < BQ; ++bb) {
            float* dst = &s_out[((size_t)(bbase + bb) * NOUT + o) * DOUT + d0];
            atomicAdd(dst,     acc0[bb] * scale);
            atomicAdd(dst + 1, acc1[bb] * scale);
        }
    } else {
        float2* base = part + (size_t)(cg * 4 + quad) * PART_PER_BLK;
#pragma unroll
        for (int bb = 0; bb < BQ; ++bb)
            base[bb * (NOUT * DOUT / 2) + o * (DOUT / 2) + dg] =
                make_float2(acc0[bb] * scale, acc1[bb] * scale);
    }
}

// ------- pass2/3: wave = bb, lane = o, two-sweep recompute, no u[] -------
__global__ __launch_bounds__(TPB2)
void caps_pass23(const float* __restrict__ W, const float* __restrict__ x,
                 const float* __restrict__ v_in, float2* __restrict__ part)
{
    const int t    = threadIdx.x;          // 0..511
    const int lane = t & 63;               // = o
    const int wid  = t >> 6;               // = bb

    const int bid  = blockIdx.x;
    const int xcd  = bid & 7;
    const int j    = bid >> 3;
    const int cg   = xcd * (CG / 8) + (j >> 2);
    const int quad = j & 3;
    const int nbase = cg * NCHB;
    const int bbase = quad * BQ;

    __shared__ float4 xs[BQ][NCHB][DIN / 4];      // 8 KB only

    {   // stage x slice: 512 float4
        const int bb = t >> 6, r = t & 63, nn = r >> 2, q = r & 3;
        xs[bb][nn][q] = ((const float4*)x)[(size_t)(bbase + bb) * (NIN * DIN / 4)
                                           + (size_t)(nbase + nn) * (DIN / 4) + q];
    }
    __syncthreads();

    // v for this (bb, o): 8 float4 = 32 persistent regs (read once, L2-resident)
    float4 v4[8];
    {
        const float4* vp = (const float4*)(v_in +
            ((size_t)(bbase + wid) * NOUT + lane) * DOUT);
#pragma unroll
        for (int q = 0; q < 8; ++q) v4[q] = vp[q];
    }

    float acc[DOUT];                               // 32 persistent regs
#pragma unroll
    for (int d = 0; d < DOUT; ++d) acc[d] = 0.f;

    for (int nn = 0; nn < NCHB; ++nn) {
        const float4 x0 = xs[wid][nn][0], x1 = xs[wid][nn][1],
                     x2 = xs[wid][nn][2], x3 = xs[wid][nn][3];
        const float4* wp = (const float4*)(W +
            ((size_t)(nbase + nn) * NOUT + lane) * (DOUT * DIN));

        // ---- sweep 1: logit = sum_d (w_d . x) * v_d  (w streamed, u not kept)
        float logit = 0.f;
#pragma unroll
        for (int d = 0; d < DOUT; ++d) {
            const float4 wa = wp[d * 4 + 0], wb = wp[d * 4 + 1],
                         wc = wp[d * 4 + 2], wd = wp[d * 4 + 3];
            const float ud = wa.x*x0.x + wa.y*x0.y + wa.z*x0.z + wa.w*x0.w
                           + wb.x*x1.x + wb.y*x1.y + wb.z*x1.z + wb.w*x1.w
                           + wc.x*x2.x + wc.y*x2.y + wc.z*x2.z + wc.w*x2.w
                           + wd.x*x3.x + wd.y*x3.y + wd.z*x3.z + wd.w*x3.w;
            logit += ud * ((const float*)v4)[d];   // static index after unroll
        }
        // in-wave softmax over o = 64 lanes (no max-sub: |logit| << 88)
        const float e = __expf(logit);
        float sm = e;
#pragma unroll
        for (int m = 1; m < 64; m <<= 1) sm += __shfl_xor(sm, m);
        const float c = e / sm;

        // prevent CSE of u across the softmax (would put 32 u's live -> spill)
        asm volatile("" ::: "memory");

        // ---- sweep 2: recompute u_d from the (L1/L2-hot) W row, accumulate
#pragma unroll
        for (int d = 0; d < DOUT; ++d) {
            const float4 wa = wp[d * 4 + 0], wb = wp[d * 4 + 1],
                         wc = wp[d * 4 + 2], wd = wp[d * 4 + 3];
            const float ud = wa.x*x0.x + wa.y*x0.y + wa.z*x0.z + wa.w*x0.w
                           + wb.x*x1.x + wb.y*x1.y + wb.z*x1.z + wb.w*x1.w
                           + wc.x*x2.x + wc.y*x2.y + wc.z*x2.z + wc.w*x2.w
                           + wd.x*x3.x + wd.y*x3.y + wd.z*x3.z + wd.w*x3.w;
            acc[d] += c * ud;
        }
    }

    // partial store, float-layout identical to round-8: [bb][o][d]
    float* pb = (float*)(part + (size_t)(cg * 4 + quad) * PART_PER_BLK)
              + (size_t)wid * (NOUT * DOUT) + lane * DOUT;
#pragma unroll
    for (int d = 0; d < DOUT; d += 4)
        *(float4*)(pb + d) = make_float4(acc[d], acc[d+1], acc[d+2], acc[d+3]);
}

// sum 128 chunk-partials per element, then squash per (b,o) row (16 lanes)
__global__ __launch_bounds__(256)
void reduce_squash(const float2* __restrict__ part, float* __restrict__ vout,
                   int accumulate)
{
    const int id = blockIdx.x * 256 + threadIdx.x;   // 0..32767
    const int dg = id & 15;
    const int o  = (id >> 4) & 63;
    const int b  = id >> 10;
    const int quad = b >> 3, bb = b & 7;
    const size_t base = (size_t)bb * (NOUT * DOUT / 2) + o * (DOUT / 2) + dg;

    float2 a0 = make_float2(0.f, 0.f), a1 = make_float2(0.f, 0.f);
    for (int cg = 0; cg < CG; cg += 2) {
        const float2 p0 = part[(size_t)(cg * 4 + quad) * PART_PER_BLK + base];
        const float2 p1 = part[(size_t)((cg + 1) * 4 + quad) * PART_PER_BLK + base];
        a0.x += p0.x; a0.y += p0.y;
        a1.x += p1.x; a1.y += p1.y;
    }
    const float sx = a0.x + a1.x, sy = a0.y + a1.y;

    float sq = sx * sx + sy * sy;
    sq += __shfl_xor(sq, 1);
    sq += __shfl_xor(sq, 2);
    sq += __shfl_xor(sq, 4);
    sq += __shfl_xor(sq, 8);        // row (b,o) = 16-lane group
    const float f = sq / ((1.0f + sq) * sqrtf(sq + 1e-8f));

    float2* vo = (float2*)vout;
    float2 r = make_float2(sx * f, sy * f);
    if (accumulate) {
        const float2 old = vo[id];
        r.x += old.x; r.y += old.y;
    }
    vo[id] = r;
}

// fallback squash for the atomic path
__global__ void squash_k(const float* __restrict__ s, float* __restrict__ vout,
                         int accumulate)
{
    const int idx = blockIdx.x * 256 + threadIdx.x;
    const float val = s[idx];
    float sq = val * val;
#pragma unroll
    for (int m = 1; m < 32; m <<= 1) sq += __shfl_xor(sq, m);
    const float f = sq / ((1.0f + sq) * sqrtf(sq + 1e-8f));
    const float v = val * f;
    if (accumulate) vout[idx] += v;
    else            vout[idx] = v;
}

extern "C" void kernel_launch(void* const* d_in, const int* in_sizes, int n_in,
                              void* d_out, int out_size, void* d_ws, size_t ws_size,
                              hipStream_t stream)
{
    (void)in_sizes; (void)n_in; (void)out_size;
    const float* x = (const float*)d_in[0];
    const float* W = (const float*)d_in[1];
    float* out = (float*)d_out;

    const size_t partBytes = (size_t)NBLK * PART_PER_BLK * sizeof(float2); // 32 MB
    const size_t vBytes    = (size_t)B_ * NOUT * DOUT * sizeof(float);     // 256 KB

    if (ws_size >= partBytes + vBytes) {
        // ---- partial-sum path (no global atomics)
        float2* part = (float2*)d_ws;
        float*  vA   = (float*)((char*)d_ws + partBytes);

        caps_pass<1, false><<<dim3(NBLK), dim3(TPB), 0, stream>>>(W, x, nullptr, nullptr, part);
        reduce_squash<<<dim3(128), dim3(256), 0, stream>>>(part, vA, 0);   // vA = v1

        caps_pass23<<<dim3(NBLK), dim3(TPB2), 0, stream>>>(W, x, vA, part);
        reduce_squash<<<dim3(128), dim3(256), 0, stream>>>(part, vA, 1);   // vA = v1+v2

        caps_pass23<<<dim3(NBLK), dim3(TPB2), 0, stream>>>(W, x, vA, part);
        reduce_squash<<<dim3(128), dim3(256), 0, stream>>>(part, out, 0);  // out = v3
    } else {
        // ---- atomic fallback
        float* s  = (float*)d_ws;
        float* vA = s + B_ * NOUT * DOUT;

        hipMemsetAsync(s, 0, vBytes, stream);
        caps_pass<1, true><<<dim3(NBLK), dim3(TPB), 0, stream>>>(W, x, nullptr, s, nullptr);
        squash_k<<<dim3(256), dim3(256), 0, stream>>>(s, vA, 0);

        hipMemsetAsync(s, 0, vBytes, stream);
        caps_pass<2, true><<<dim3(NBLK), dim3(TPB), 0, stream>>>(W, x, vA, s, nullptr);
        squash_k<<<dim3(256), dim3(256), 0, stream>>>(s, vA, 1);

        hipMemsetAsync(s, 0, vBytes, stream);
        caps_pass<2, true><<<dim3(NBLK), dim3(TPB), 0, stream>>>(W, x, vA, s, nullptr);
        squash_k<<<dim3(256), dim3(256), 0, stream>>>(s, out, 0);
    }
}

// Round 11
// 972.533 us; speedup vs baseline: 3.8987x; 3.8987x over previous
//
#include <hip/hip_runtime.h>

// RoutingCapsules on MI355X (gfx950)
// x: [B=32, Nin=2048, Din=16] f32
// W: [1, Nin=2048, Nout=64, Dout=32, Din=16] f32
// out v: [B=32, Nout=64, Dout=32] f32
//
// 3 fused W-sweeps (u_hat recomputed, never materialized):
//   pass1: c uniform     -> s1 -> v1
//   pass2: logits=u.v1   -> s2 -> v2
//   pass3: logits=u.(v1+v2)   -> v3 = out
//
// Round-11: round 10 proved lane=o W reads are uncoalesced (64 lines/instr,
// 128KB/wave/n >> 32KB L1 -> latency-bound, 1850us). Round 8 (599us) was
// DS-pipe-bound: 56 LDS-pipe ops vs 64 FMA4 per thread per nn (one LDS unit
// per 4 SIMDs). This round: TPB=512 (allocator grants ~124 VGPR, measured
// r9/r10) so u[4][4]+acc[4][4] stay in REGS across the softmax barriers
// (no ustash). BQ=4, thread=(o, dg 0..7) owns a d-quad: logit = 4 in-thread
// MAC + 3 shfl (vs 32). x loaded via block-uniform addresses -> scalar cache,
// zero DS/vector ops. W keeps the round-8 coalesced pattern.

#define B_   32
#define NIN  2048
#define DIN  16
#define NOUT 64
#define DOUT 32
#define BQ   4                          // batches per block
#define NCHB 16                         // n per block
#define CG   (NIN / NCHB)               // 128 chunk-groups
#define NQ   (B_ / BQ)                  // 8 quads
#define NBLK (CG * NQ)                  // 1024 blocks
#define TPB  512
#define PART_PER_BLK (BQ * NOUT * DOUT / 2)   // 4096 float2 per block (32 KB)

template<int PASS, bool ATOMIC>
__global__ __launch_bounds__(TPB)
void caps_pass(const float* __restrict__ W, const float* __restrict__ x,
               const float* __restrict__ v_in, float* __restrict__ s_out,
               float2* __restrict__ part)
{
    const int t    = threadIdx.x;     // 0..511
    const int o    = t >> 3;          // 0..63  capsule-out
    const int dg   = t & 7;           // 0..7   d-quad index
    const int d0   = dg << 2;         // 0,4,..,28
    const int lane = t & 63;
    const int wid  = t >> 6;          // wave 0..7

    // Swizzle: 8 quad-siblings (same n-chunk) adjacent on the same XCD ->
    // shared 2 MB W chunk served once from HBM, 7x from L2/L3.
    const int bid  = blockIdx.x;
    const int xcd  = bid & 7;
    const int j    = bid >> 3;                    // 0..127
    const int cg   = xcd * (CG / 8) + (j >> 3);   // 0..127
    const int quad = j & 7;                       // 0..7
    const int nbase = cg * NCHB;
    const int bbase = quad * BQ;

    __shared__ float lg[BQ][NOUT];                // 1 KB logits
    __shared__ float cs[BQ][NOUT];                // 1 KB softmax weights

    // v for this thread's (bb, o, d-quad): 4 float4 = 16 persistent regs
    float4 v4[BQ];
    if (PASS != 1) {
#pragma unroll
        for (int bb = 0; bb < BQ; ++bb)
            v4[bb] = *(const float4*)(v_in +
                ((size_t)(bbase + bb) * NOUT + o) * DOUT + d0);
    }

    float acc[BQ][4];                             // 16 persistent regs
#pragma unroll
    for (int bb = 0; bb < BQ; ++bb)
#pragma unroll
        for (int q = 0; q < 4; ++q) acc[bb][q] = 0.f;

    for (int nn = 0; nn < NCHB; ++nn) {
        const int n = nbase + nn;
        // W rows d0..d0+3 of W[n][o]: 16 float4, streamed 4 at a time
        const float4* wp = (const float4*)(W +
            (((size_t)n * NOUT + o) * DOUT + d0) * DIN);

        float u[BQ][4];                           // 16 regs, live across barriers
#pragma unroll
        for (int bb = 0; bb < BQ; ++bb)
#pragma unroll
            for (int q = 0; q < 4; ++q) u[bb][q] = 0.f;

#pragma unroll
        for (int dd = 0; dd < 4; ++dd) {          // one W row (16 floats) at a time
            const float4 wa = wp[dd * 4 + 0], wb = wp[dd * 4 + 1],
                         wc = wp[dd * 4 + 2], wd = wp[dd * 4 + 3];
#pragma unroll
            for (int bb = 0; bb < BQ; ++bb) {
                // x is block-uniform -> scalar loads (SGPR), no vector/DS ops
                const float4* xu = (const float4*)(x +
                    ((size_t)(bbase + bb) * NIN + n) * DIN);
                const float4 x0 = xu[0], x1 = xu[1], x2 = xu[2], x3 = xu[3];
                u[bb][dd] += wa.x*x0.x + wa.y*x0.y + wa.z*x0.z + wa.w*x0.w
                           + wb.x*x1.x + wb.y*x1.y + wb.z*x1.z + wb.w*x1.w
                           + wc.x*x2.x + wc.y*x2.y + wc.z*x2.z + wc.w*x2.w
                           + wd.x*x3.x + wd.y*x3.y + wd.z*x3.z + wd.w*x3.w;
            }
        }

        if constexpr (PASS == 1) {
#pragma unroll
            for (int bb = 0; bb < BQ; ++bb)
#pragma unroll
                for (int q = 0; q < 4; ++q) acc[bb][q] += u[bb][q];
        } else {
            // logit partial: in-thread 4 MAC, then 3-shfl reduce over 8 dg
#pragma unroll
            for (int bb = 0; bb < BQ; ++bb) {
                float p = u[bb][0]*v4[bb].x + u[bb][1]*v4[bb].y
                        + u[bb][2]*v4[bb].z + u[bb][3]*v4[bb].w;
                p += __shfl_xor(p, 1);
                p += __shfl_xor(p, 2);
                p += __shfl_xor(p, 4);            // full 32-d dot
                if (dg == 0) lg[bb][o] = p;
            }
            __syncthreads();
            // softmax dedup: wave bb (0..3) handles batch bb, lane = o
            if (wid < BQ) {
                const float e = __expf(lg[wid][lane]);  // |logit| << 88
                float sm = e;
#pragma unroll
                for (int m = 1; m < 64; m <<= 1) sm += __shfl_xor(sm, m);
                cs[wid][lane] = e / sm;
            }
            __syncthreads();
#pragma unroll
            for (int bb = 0; bb < BQ; ++bb) {
                const float c = cs[bb][o];        // 8-lane broadcast read
#pragma unroll
                for (int q = 0; q < 4; ++q) acc[bb][q] += c * u[bb][q];
            }
        }
    }

    const float scale = (PASS == 1) ? (1.0f / 64.0f) : 1.0f;
    if constexpr (ATOMIC) {
#pragma unroll
        for (int bb = 0; bb < BQ; ++bb) {
            float* dst = &s_out[((size_t)(bbase + bb) * NOUT + o) * DOUT + d0];
#pragma unroll
            for (int q = 0; q < 4; ++q) atomicAdd(dst + q, acc[bb][q] * scale);
        }
    } else {
        // coalesced partial store: part[cg*8+quad][bb][o][d] (float4/thread)
        float* pb = (float*)(part + (size_t)(cg * 8 + quad) * PART_PER_BLK);
#pragma unroll
        for (int bb = 0; bb < BQ; ++bb)
            *(float4*)(pb + bb * (NOUT * DOUT) + o * DOUT + d0) =
                make_float4(acc[bb][0]*scale, acc[bb][1]*scale,
                            acc[bb][2]*scale, acc[bb][3]*scale);
    }
}

// sum 128 chunk-partials per element, then squash per (b,o) row (16 lanes)
__global__ __launch_bounds__(256)
void reduce_squash(const float2* __restrict__ part, float* __restrict__ vout,
                   int accumulate)
{
    const int id = blockIdx.x * 256 + threadIdx.x;   // 0..32767 (float2 granule)
    const int dg2 = id & 15;          // float2 index within the 32-d row
    const int o   = (id >> 4) & 63;
    const int b   = id >> 10;         // 0..31
    const int quad = b >> 2, bb = b & 3;
    const size_t base = (size_t)bb * (NOUT * DOUT / 2) + o * (DOUT / 2) + dg2;

    float2 a0 = make_float2(0.f, 0.f), a1 = make_float2(0.f, 0.f);
    for (int cg = 0; cg < CG; cg += 2) {
        const float2 p0 = part[(size_t)(cg * 8 + quad) * PART_PER_BLK + base];
        const float2 p1 = part[(size_t)((cg + 1) * 8 + quad) * PART_PER_BLK + base];
        a0.x += p0.x; a0.y += p0.y;
        a1.x += p1.x; a1.y += p1.y;
    }
    const float sx = a0.x + a1.x, sy = a0.y + a1.y;

    float sq = sx * sx + sy * sy;
    sq += __shfl_xor(sq, 1);
    sq += __shfl_xor(sq, 2);
    sq += __shfl_xor(sq, 4);
    sq += __shfl_xor(sq, 8);        // row (b,o) = 16-lane group
    const float f = sq / ((1.0f + sq) * sqrtf(sq + 1e-8f));

    float2* vo = (float2*)vout;
    float2 r = make_float2(sx * f, sy * f);
    if (accumulate) {
        const float2 old = vo[id];
        r.x += old.x; r.y += old.y;
    }
    vo[id] = r;
}

// fallback squash for the atomic path
__global__ void squash_k(const float* __restrict__ s, float* __restrict__ vout,
                         int accumulate)
{
    const int idx = blockIdx.x * 256 + threadIdx.x;
    const float val = s[idx];
    float sq = val * val;
#pragma unroll
    for (int m = 1; m < 32; m <<= 1) sq += __shfl_xor(sq, m);
    const float f = sq / ((1.0f + sq) * sqrtf(sq + 1e-8f));
    const float v = val * f;
    if (accumulate) vout[idx] += v;
    else            vout[idx] = v;
}

extern "C" void kernel_launch(void* const* d_in, const int* in_sizes, int n_in,
                              void* d_out, int out_size, void* d_ws, size_t ws_size,
                              hipStream_t stream)
{
    (void)in_sizes; (void)n_in; (void)out_size;
    const float* x = (const float*)d_in[0];
    const float* W = (const float*)d_in[1];
    float* out = (float*)d_out;

    const size_t partBytes = (size_t)NBLK * PART_PER_BLK * sizeof(float2); // 32 MB
    const size_t vBytes    = (size_t)B_ * NOUT * DOUT * sizeof(float);     // 256 KB

    if (ws_size >= partBytes + vBytes) {
        // ---- partial-sum path (no global atomics)
        float2* part = (float2*)d_ws;
        float*  vA   = (float*)((char*)d_ws + partBytes);

        caps_pass<1, false><<<dim3(NBLK), dim3(TPB), 0, stream>>>(W, x, nullptr, nullptr, part);
        reduce_squash<<<dim3(128), dim3(256), 0, stream>>>(part, vA, 0);   // vA = v1

        caps_pass<2, false><<<dim3(NBLK), dim3(TPB), 0, stream>>>(W, x, vA, nullptr, part);
        reduce_squash<<<dim3(128), dim3(256), 0, stream>>>(part, vA, 1);   // vA = v1+v2

        caps_pass<2, false><<<dim3(NBLK), dim3(TPB), 0, stream>>>(W, x, vA, nullptr, part);
        reduce_squash<<<dim3(128), dim3(256), 0, stream>>>(part, out, 0);  // out = v3
    } else {
        // ---- atomic fallback
        float* s  = (float*)d_ws;
        float* vA = s + B_ * NOUT * DOUT;

        hipMemsetAsync(s, 0, vBytes, stream);
        caps_pass<1, true><<<dim3(NBLK), dim3(TPB), 0, stream>>>(W, x, nullptr, s, nullptr);
        squash_k<<<dim3(256), dim3(256), 0, stream>>>(s, vA, 0);

        hipMemsetAsync(s, 0, vBytes, stream);
        caps_pass<2, true><<<dim3(NBLK), dim3(TPB), 0, stream>>>(W, x, vA, s, nullptr);
        squash_k<<<dim3(256), dim3(256), 0, stream>>>(s, vA, 1);

        hipMemsetAsync(s, 0, vBytes, stream);
        caps_pass<2, true><<<dim3(NBLK), dim3(TPB), 0, stream>>>(W, x, vA, s, nullptr);
        squash_k<<<dim3(256), dim3(256), 0, stream>>>(s, out, 0);
    }
}

// Round 12
// 723.039 us; speedup vs baseline: 5.2440x; 1.3451x over previous
//
#include <hip/hip_runtime.h>

// RoutingCapsules on MI355X (gfx950)
// x: [B=32, Nin=2048, Din=16] f32
// W: [1, Nin=2048, Nout=64, Dout=32, Din=16] f32
// out v: [B=32, Nout=64, Dout=32] f32
//
// 3 fused W-sweeps (u_hat recomputed, never materialized):
//   pass1: c uniform     -> s1 -> v1
//   pass2: logits=u.v1   -> s2 -> v2
//   pass3: logits=u.(v1+v2)   -> v3 = out
//
// Round-12 synthesis of three measured facts:
//  (a) r11: softmax machinery (shfl+2 barriers) is FREE next to W access --
//      both r11 passes ~335us; the cost was the 256B/thread W fragment
//      (2x line-touches of r8's 128B) + global x.
//  (b) L1 line-touch arithmetic: r8's T=67e6 touches <-> ~75us/pass.
//  (c) TPB=512 unlocks ~124 VGPR (r10/r11, no spill) vs TPB=1024's 64.
// Design: TPB=512, BQ=8 (redundancy 4 -> r8-equal T), thread=(o,dg0..7)
// owns a d-quad; u[8][4] register-resident across softmax barriers (no
// ustash); logit = in-thread 4-MAC + 3 shfl; v re-read per nn from L2
// (8 coalesced loads) instead of held in regs; x LDS-broadcast. All 8
// waves run the softmax phase. Partial layout identical to r8.

#define B_   32
#define NIN  2048
#define DIN  16
#define NOUT 64
#define DOUT 32
#define BQ   8                          // batches per block
#define NCHB 16                         // n per block
#define CG   (NIN / NCHB)               // 128 chunk-groups
#define NBLK (CG * (B_ / BQ))           // 512 blocks
#define TPB  512
#define PART_PER_BLK (BQ * NOUT * DOUT / 2)   // 8192 float2 per block (64 KB)

template<int PASS, bool ATOMIC>
__global__ __launch_bounds__(TPB)
void caps_pass(const float* __restrict__ W, const float* __restrict__ x,
               const float* __restrict__ v_in, float* __restrict__ s_out,
               float2* __restrict__ part)
{
    const int t    = threadIdx.x;     // 0..511
    const int o    = t >> 3;          // 0..63  capsule-out
    const int dg   = t & 7;           // 0..7
    const int d0   = dg << 2;         // d-quad base: 0,4,..,28
    const int lane = t & 63;
    const int wid  = t >> 6;          // wave 0..7

    // Swizzle: 4 quad-siblings (same n-chunk) adjacent on the same XCD ->
    // shared 2 MB W chunk served once from HBM, 3x from L2.
    const int bid  = blockIdx.x;
    const int xcd  = bid & 7;
    const int j    = bid >> 3;                    // 0..63
    const int cg   = xcd * (CG / 8) + (j >> 2);   // 0..127
    const int quad = j & 3;                       // 0..3
    const int nbase = cg * NCHB;
    const int bbase = quad * BQ;

    __shared__ float4 xs[BQ][NCHB * DIN / 4];     // 8 KB: x[bquad][16 n][16 i]
    __shared__ float  lg[BQ][NOUT];               // 2 KB logits
    __shared__ float  cs[BQ][NOUT];               // 2 KB softmax weights

    {   // stage x slice once: 512 float4, one per thread
        const int bb = t >> 6;
        const int k  = t & 63;                    // nn*4+q
        xs[bb][k] = ((const float4*)x)[(size_t)(bbase + bb) * (NIN * DIN / 4)
                                       + (size_t)nbase * (DIN / 4) + k];
    }

    float acc[BQ][4];                             // 32 persistent regs
#pragma unroll
    for (int bb = 0; bb < BQ; ++bb)
#pragma unroll
        for (int dd = 0; dd < 4; ++dd) acc[bb][dd] = 0.f;

    __syncthreads();

    for (int nn = 0; nn < NCHB; ++nn) {
        // W fragment: rows d0..d0+3 of W[n][o] = 64 consecutive floats.
        // wp[dd*4+q] = row d0+dd, i-chunk q. Streamed 4 rows x 1 chunk at a
        // time (w live = 16 regs transient).
        const float4* wp = (const float4*)(W +
            (((size_t)(nbase + nn) * NOUT + o) * DOUT + d0) * DIN);

        float u[BQ][4];                           // 32 regs, live across barriers
#pragma unroll
        for (int bb = 0; bb < BQ; ++bb)
#pragma unroll
            for (int dd = 0; dd < 4; ++dd) u[bb][dd] = 0.f;

#pragma unroll
        for (int q = 0; q < 4; ++q) {             // i-chunk outer: x read once/bb
            const float4 w0 = wp[0 * 4 + q];
            const float4 w1 = wp[1 * 4 + q];
            const float4 w2 = wp[2 * 4 + q];
            const float4 w3 = wp[3 * 4 + q];
#pragma unroll
            for (int bb = 0; bb < BQ; ++bb) {
                const float4 xq = xs[bb][nn * 4 + q];   // LDS broadcast
                u[bb][0] += w0.x*xq.x + w0.y*xq.y + w0.z*xq.z + w0.w*xq.w;
                u[bb][1] += w1.x*xq.x + w1.y*xq.y + w1.z*xq.z + w1.w*xq.w;
                u[bb][2] += w2.x*xq.x + w2.y*xq.y + w2.z*xq.z + w2.w*xq.w;
                u[bb][3] += w3.x*xq.x + w3.y*xq.y + w3.z*xq.z + w3.w*xq.w;
            }
        }

        if constexpr (PASS == 1) {
#pragma unroll
            for (int bb = 0; bb < BQ; ++bb)
#pragma unroll
                for (int dd = 0; dd < 4; ++dd) acc[bb][dd] += u[bb][dd];
        } else {
            // logit partial: in-thread 4 MAC + 3-shfl reduce over 8 dg lanes.
            // v re-read per nn (L2-hot 256 KB, coalesced) instead of held.
#pragma unroll
            for (int bb = 0; bb < BQ; ++bb) {
                const float4 vv = *(const float4*)(v_in +
                    ((size_t)(bbase + bb) * NOUT + o) * DOUT + d0);
                float p = u[bb][0]*vv.x + u[bb][1]*vv.y
                        + u[bb][2]*vv.z + u[bb][3]*vv.w;
                p += __shfl_xor(p, 1);
                p += __shfl_xor(p, 2);
                p += __shfl_xor(p, 4);            // full 32-d dot
                if (dg == 0) lg[bb][o] = p;
            }
            __syncthreads();
            // softmax dedup: ALL 8 waves active, wave wid handles batch wid
            {
                const float e = __expf(lg[wid][lane]);  // |logit| << 88
                float sm = e;
#pragma unroll
                for (int m = 1; m < 64; m <<= 1) sm += __shfl_xor(sm, m);
                cs[wid][lane] = e / sm;
            }
            __syncthreads();
#pragma unroll
            for (int bb = 0; bb < BQ; ++bb) {
                const float c = cs[bb][o];        // broadcast read
#pragma unroll
                for (int dd = 0; dd < 4; ++dd) acc[bb][dd] += c * u[bb][dd];
            }
        }
    }

    const float scale = (PASS == 1) ? (1.0f / 64.0f) : 1.0f;
    if constexpr (ATOMIC) {
#pragma unroll
        for (int bb = 0; bb < BQ; ++bb) {
            float* dst = &s_out[((size_t)(bbase + bb) * NOUT + o) * DOUT + d0];
#pragma unroll
            for (int dd = 0; dd < 4; ++dd) atomicAdd(dst + dd, acc[bb][dd] * scale);
        }
    } else {
        // coalesced partial store, float-layout identical to r8: [bb][o][d]
        float* pb = (float*)(part + (size_t)(cg * 4 + quad) * PART_PER_BLK);
#pragma unroll
        for (int bb = 0; bb < BQ; ++bb)
            *(float4*)(pb + bb * (NOUT * DOUT) + o * DOUT + d0) =
                make_float4(acc[bb][0]*scale, acc[bb][1]*scale,
                            acc[bb][2]*scale, acc[bb][3]*scale);
    }
}

// sum 128 chunk-partials per element, then squash per (b,o) row (16 lanes)
__global__ __launch_bounds__(256)
void reduce_squash(const float2* __restrict__ part, float* __restrict__ vout,
                   int accumulate)
{
    const int id = blockIdx.x * 256 + threadIdx.x;   // 0..32767
    const int dg = id & 15;
    const int o  = (id >> 4) & 63;
    const int b  = id >> 10;
    const int quad = b >> 3, bb = b & 7;
    const size_t base = (size_t)bb * (NOUT * DOUT / 2) + o * (DOUT / 2) + dg;

    float2 a0 = make_float2(0.f, 0.f), a1 = make_float2(0.f, 0.f);
    for (int cg = 0; cg < CG; cg += 2) {
        const float2 p0 = part[(size_t)(cg * 4 + quad) * PART_PER_BLK + base];
        const float2 p1 = part[(size_t)((cg + 1) * 4 + quad) * PART_PER_BLK + base];
        a0.x += p0.x; a0.y += p0.y;
        a1.x += p1.x; a1.y += p1.y;
    }
    const float sx = a0.x + a1.x, sy = a0.y + a1.y;

    float sq = sx * sx + sy * sy;
    sq += __shfl_xor(sq, 1);
    sq += __shfl_xor(sq, 2);
    sq += __shfl_xor(sq, 4);
    sq += __shfl_xor(sq, 8);        // row (b,o) = 16-lane group
    const float f = sq / ((1.0f + sq) * sqrtf(sq + 1e-8f));

    float2* vo = (float2*)vout;
    float2 r = make_float2(sx * f, sy * f);
    if (accumulate) {
        const float2 old = vo[id];
        r.x += old.x; r.y += old.y;
    }
    vo[id] = r;
}

// fallback squash for the atomic path
__global__ void squash_k(const float* __restrict__ s, float* __restrict__ vout,
                         int accumulate)
{
    const int idx = blockIdx.x * 256 + threadIdx.x;
    const float val = s[idx];
    float sq = val * val;
#pragma unroll
    for (int m = 1; m < 32; m <<= 1) sq += __shfl_xor(sq, m);
    const float f = sq / ((1.0f + sq) * sqrtf(sq + 1e-8f));
    const float v = val * f;
    if (accumulate) vout[idx] += v;
    else            vout[idx] = v;
}

extern "C" void kernel_launch(void* const* d_in, const int* in_sizes, int n_in,
                              void* d_out, int out_size, void* d_ws, size_t ws_size,
                              hipStream_t stream)
{
    (void)in_sizes; (void)n_in; (void)out_size;
    const float* x = (const float*)d_in[0];
    const float* W = (const float*)d_in[1];
    float* out = (float*)d_out;

    const size_t partBytes = (size_t)NBLK * PART_PER_BLK * sizeof(float2); // 32 MB
    const size_t vBytes    = (size_t)B_ * NOUT * DOUT * sizeof(float);     // 256 KB

    if (ws_size >= partBytes + vBytes) {
        // ---- partial-sum path (no global atomics)
        float2* part = (float2*)d_ws;
        float*  vA   = (float*)((char*)d_ws + partBytes);

        caps_pass<1, false><<<dim3(NBLK), dim3(TPB), 0, stream>>>(W, x, nullptr, nullptr, part);
        reduce_squash<<<dim3(128), dim3(256), 0, stream>>>(part, vA, 0);   // vA = v1

        caps_pass<2, false><<<dim3(NBLK), dim3(TPB), 0, stream>>>(W, x, vA, nullptr, part);
        reduce_squash<<<dim3(128), dim3(256), 0, stream>>>(part, vA, 1);   // vA = v1+v2

        caps_pass<2, false><<<dim3(NBLK), dim3(TPB), 0, stream>>>(W, x, vA, nullptr, part);
        reduce_squash<<<dim3(128), dim3(256), 0, stream>>>(part, out, 0);  // out = v3
    } else {
        // ---- atomic fallback
        float* s  = (float*)d_ws;
        float* vA = s + B_ * NOUT * DOUT;

        hipMemsetAsync(s, 0, vBytes, stream);
        caps_pass<1, true><<<dim3(NBLK), dim3(TPB), 0, stream>>>(W, x, nullptr, s, nullptr);
        squash_k<<<dim3(256), dim3(256), 0, stream>>>(s, vA, 0);

        hipMemsetAsync(s, 0, vBytes, stream);
        caps_pass<2, true><<<dim3(NBLK), dim3(TPB), 0, stream>>>(W, x, vA, s, nullptr);
        squash_k<<<dim3(256), dim3(256), 0, stream>>>(s, vA, 1);

        hipMemsetAsync(s, 0, vBytes, stream);
        caps_pass<2, true><<<dim3(NBLK), dim3(TPB), 0, stream>>>(W, x, vA, s, nullptr);
        squash_k<<<dim3(256), dim3(256), 0, stream>>>(s, out, 0);
    }
}